// Round 2
// baseline (882.733 us; speedup 1.0000x reference)
//
#include <hip/hip_runtime.h>
#include <hip/hip_fp16.h>

typedef float    f32x4 __attribute__((ext_vector_type(4)));
typedef _Float16 f16x4 __attribute__((ext_vector_type(4)));
typedef _Float16 f16x8 __attribute__((ext_vector_type(8)));

#define NHEADS 64
#define DIM    512
#define HID    2048
#define BM     128
#define BN     128
#define BK     32
#define NCHUNK (HID / BN)   // 16
#define KSTEP  (DIM / BK)   // 16
#define LDS_PITCH 40        // halfs per row: 32 data + 8 pad (80 B -> bank stride 20)
#define A_HALFS (BM * LDS_PITCH)             // 5120
#define BUF_HALFS (A_HALFS + BN * LDS_PITCH) // 10240

__global__ __launch_bounds__(256, 2)
void mhmlp_fused(const float* __restrict__ x,
                 const float* __restrict__ W1,
                 const float* __restrict__ b1,
                 const float* __restrict__ W2,
                 const float* __restrict__ b2,
                 float* __restrict__ out)
{
    __shared__ _Float16 lds[2][BUF_HALFS];

    const int tid  = threadIdx.x;
    const int lane = tid & 63;
    const int wid  = tid >> 6;
    const int wr   = wid >> 1;      // wave row 0..1 (64 rows each)
    const int wc   = wid & 1;       // wave col 0..1 (64 cols each)
    const int lrow = lane & 15;     // fragment col within 16 (C/D: col = lane&15)
    const int lkb  = lane >> 4;     // C/D: row = (lane>>4)*4 + reg

    // XCD swizzle: all 16 row-tiles of one head land on one XCD (W1_h stays in its L2)
    const int bid  = (int)blockIdx.x;
    const int xcd  = bid & 7;
    const int idx  = bid >> 3;              // 0..127
    const int head = (idx >> 4) * 8 + xcd;  // 0..63
    const int rt   = idx & 15;
    const int b0   = rt * BM;

    const float* __restrict__ W1h = W1 + (size_t)head * DIM * HID;

    // staging geometry
    const int a_r   = tid >> 3;    // A row within 32-row slab (+32*i)
    const int a_k4  = tid & 7;     // A k-quad
    const int b_n   = tid & 127;   // B column (n) owned by this thread
    const int b_dqb = tid >> 7;    // 0..1 ; d-quad = 2*i + b_dqb

    f32x4 s_acc[4];                 // second-layer partials: [m][r]
    #pragma unroll
    for (int m = 0; m < 4; ++m) s_acc[m] = (f32x4)0.f;

    #pragma unroll 1
    for (int nc = 0; nc < NCHUNK; ++nc) {
        const int n0 = nc * BN;

        f32x4 acc[4][4];
        #pragma unroll
        for (int m = 0; m < 4; ++m)
            #pragma unroll
            for (int n = 0; n < 4; ++n) acc[m][n] = (f32x4)0.f;

        // ---- prologue: stage ks=0 into buf 0 ----
        {
            f32x4 aq[4];
            float bv[4][4];
            #pragma unroll
            for (int i = 0; i < 4; ++i)
                aq[i] = *(const f32x4*)&x[(size_t)(b0 + i*32 + a_r) * DIM + a_k4*4];
            #pragma unroll
            for (int i = 0; i < 4; ++i) {
                const int d = (2*i + b_dqb) * 4;
                #pragma unroll
                for (int j = 0; j < 4; ++j)
                    bv[i][j] = W1h[(size_t)(d + j) * HID + n0 + b_n];
            }
            #pragma unroll
            for (int i = 0; i < 4; ++i) {
                f16x4 h;
                #pragma unroll
                for (int j = 0; j < 4; ++j) h[j] = (_Float16)aq[i][j];
                *(f16x4*)&lds[0][(i*32 + a_r) * LDS_PITCH + a_k4*4] = h;
            }
            #pragma unroll
            for (int i = 0; i < 4; ++i) {
                f16x4 h;
                #pragma unroll
                for (int j = 0; j < 4; ++j) h[j] = (_Float16)bv[i][j];
                *(f16x4*)&lds[0][A_HALFS + b_n * LDS_PITCH + (2*i + b_dqb)*4] = h;
            }
        }

        int buf = 0;
        #pragma unroll 1
        for (int ks = 0; ks < KSTEP; ++ks) {
            __syncthreads();

            const bool pre = (ks + 1) < KSTEP;
            f32x4 aq[4];
            float bv[4][4];
            if (pre) {
                const int d0 = (ks + 1) * BK;
                #pragma unroll
                for (int i = 0; i < 4; ++i)
                    aq[i] = *(const f32x4*)&x[(size_t)(b0 + i*32 + a_r) * DIM + d0 + a_k4*4];
                #pragma unroll
                for (int i = 0; i < 4; ++i) {
                    const int d = d0 + (2*i + b_dqb) * 4;
                    #pragma unroll
                    for (int j = 0; j < 4; ++j)
                        bv[i][j] = W1h[(size_t)(d + j) * HID + n0 + b_n];
                }
            }

            // ---- compute current buffer ----
            {
                f16x8 af[4], bf[4];
                #pragma unroll
                for (int m = 0; m < 4; ++m)
                    af[m] = *(const f16x8*)&lds[buf][(wr*64 + m*16 + lrow) * LDS_PITCH + lkb*8];
                #pragma unroll
                for (int n = 0; n < 4; ++n)
                    bf[n] = *(const f16x8*)&lds[buf][A_HALFS + (wc*64 + n*16 + lrow) * LDS_PITCH + lkb*8];
                #pragma unroll
                for (int m = 0; m < 4; ++m)
                    #pragma unroll
                    for (int n = 0; n < 4; ++n)
                        acc[m][n] = __builtin_amdgcn_mfma_f32_16x16x32_f16(af[m], bf[n], acc[m][n], 0, 0, 0);
            }

            // ---- convert + write next tile ----
            if (pre) {
                const int nb = buf ^ 1;
                #pragma unroll
                for (int i = 0; i < 4; ++i) {
                    f16x4 h;
                    #pragma unroll
                    for (int j = 0; j < 4; ++j) h[j] = (_Float16)aq[i][j];
                    *(f16x4*)&lds[nb][(i*32 + a_r) * LDS_PITCH + a_k4*4] = h;
                }
                #pragma unroll
                for (int i = 0; i < 4; ++i) {
                    f16x4 h;
                    #pragma unroll
                    for (int j = 0; j < 4; ++j) h[j] = (_Float16)bv[i][j];
                    *(f16x4*)&lds[nb][A_HALFS + b_n * LDS_PITCH + (2*i + b_dqb)*4] = h;
                }
            }
            buf ^= 1;
        }

        // ---- fused epilogue for this n-chunk: +b1, lrelu, *W2, accumulate ----
        #pragma unroll
        for (int nf = 0; nf < 4; ++nf) {
            const int colg = n0 + wc*64 + nf*16 + lrow;
            const float b1v = b1[head * HID + colg];
            const float w2v = W2[head * HID + colg];
            #pragma unroll
            for (int m = 0; m < 4; ++m)
                #pragma unroll
                for (int r = 0; r < 4; ++r) {
                    float v = acc[m][nf][r] + b1v;
                    v = (v >= 0.f) ? v : 0.01f * v;
                    s_acc[m][r] += v * w2v;
                }
        }
    }

    // ---- reduce across the 16 columns held by lanes (bits 0..3) ----
    #pragma unroll
    for (int m = 0; m < 4; ++m)
        #pragma unroll
        for (int r = 0; r < 4; ++r) {
            float v = s_acc[m][r];
            v += __shfl_xor(v, 1);
            v += __shfl_xor(v, 2);
            v += __shfl_xor(v, 4);
            v += __shfl_xor(v, 8);
            s_acc[m][r] = v;
        }

    // ---- cross-wave (wc) reduction: wc=1 stashes, wc=0 combines + stores ----
    __syncthreads();                       // all LDS reads of K-loop done
    float* red = (float*)&lds[0][0];       // reuse staging LDS: 128 floats
    if (wc == 1 && lrow == 0) {
        #pragma unroll
        for (int m = 0; m < 4; ++m)
            #pragma unroll
            for (int r = 0; r < 4; ++r)
                red[wr*64 + m*16 + lkb*4 + r] = s_acc[m][r];
    }
    __syncthreads();

    if (wc == 0 && lrow == 0) {
        const float b2v = b2[head];
        #pragma unroll
        for (int m = 0; m < 4; ++m)
            #pragma unroll
            for (int r = 0; r < 4; ++r) {
                const int row = wr*64 + m*16 + lkb*4 + r;
                float v = s_acc[m][r] + red[row] + b2v;
                v = (v >= 0.f) ? v : 0.01f * v;
                out[(size_t)(b0 + row) * NHEADS + head] = v;
            }
    }
}

extern "C" void kernel_launch(void* const* d_in, const int* in_sizes, int n_in,
                              void* d_out, int out_size, void* d_ws, size_t ws_size,
                              hipStream_t stream)
{
    const float* x  = (const float*)d_in[0];
    const float* W1 = (const float*)d_in[1];
    const float* b1 = (const float*)d_in[2];
    const float* W2 = (const float*)d_in[3];
    const float* b2 = (const float*)d_in[4];
    float* out = (float*)d_out;

    // grid: 16 row-tiles x 64 heads = 1024 workgroups
    mhmlp_fused<<<dim3(1024), dim3(256), 0, stream>>>(x, W1, b1, W2, b2, out);
}